// Round 1
// baseline (554.709 us; speedup 1.0000x reference)
//
#include <hip/hip_runtime.h>

#define A_COUNT 24576
#define B_COUNT 32
#define NOBJ 16
#define C_COUNT 21

__device__ __forceinline__ unsigned long long pack_key(float iou, int a) {
    unsigned int ib = __float_as_uint(iou);  // iou >= 0 so uint order == float order
    return ((unsigned long long)ib << 32) | (unsigned long long)(0xFFFFFFFFu - (unsigned int)a);
}

// Kernel 1: per-truth best prior (argmax over anchors, smallest-a tie-break)
__global__ __launch_bounds__(256) void k_match(const float4* __restrict__ anchors,
                                               const float4* __restrict__ truths,
                                               unsigned long long* __restrict__ bp_key) {
    __shared__ float4 s_t[NOBJ];
    __shared__ float s_area[NOBJ];
    const int b = blockIdx.y;
    const int a = blockIdx.x * 256 + threadIdx.x;
    if (threadIdx.x < NOBJ) {
        float4 t = truths[b * NOBJ + threadIdx.x];
        s_t[threadIdx.x] = t;
        s_area[threadIdx.x] = (t.z - t.x) * (t.w - t.y);
    }
    __syncthreads();
    float4 an = anchors[a];
    float ax0 = an.x - an.z * 0.5f, ay0 = an.y - an.w * 0.5f;
    float ax1 = an.x + an.z * 0.5f, ay1 = an.y + an.w * 0.5f;
    float area_p = (ax1 - ax0) * (ay1 - ay0);
    float iou[NOBJ];
#pragma unroll
    for (int n = 0; n < NOBJ; ++n) {
        float4 t = s_t[n];
        float lx = fmaxf(t.x, ax0), ly = fmaxf(t.y, ay0);
        float rx = fminf(t.z, ax1), ry = fminf(t.w, ay1);
        float w = fmaxf(rx - lx, 0.0f), h = fmaxf(ry - ly, 0.0f);
        float inter = w * h;
        iou[n] = inter / (s_area[n] + area_p - inter);
    }
#pragma unroll
    for (int n = 0; n < NOBJ; ++n) {
        float m = iou[n];
#pragma unroll
        for (int s = 32; s >= 1; s >>= 1) m = fmaxf(m, __shfl_xor(m, s));
        if (iou[n] == m) {
            atomicMax(&bp_key[b * NOBJ + n], pack_key(iou[n], a));
        }
    }
}

__device__ __forceinline__ float sl1(float d) {
    float ad = fabsf(d);
    return (ad < 1.0f) ? 0.5f * d * d : ad - 0.5f;
}

// Kernel 2: per-anchor match + override + smooth-L1 + focal loss
__global__ __launch_bounds__(256) void k_loss(const float* __restrict__ cls,
                                              const float4* __restrict__ locp,
                                              const float4* __restrict__ truths,
                                              const float4* __restrict__ anchors,
                                              const int* __restrict__ labels,
                                              const unsigned long long* __restrict__ bp_key,
                                              double* __restrict__ sums,
                                              unsigned int* __restrict__ cnt) {
    __shared__ float4 s_t[NOBJ];
    __shared__ float s_area[NOBJ];
    __shared__ int s_lab[NOBJ];
    __shared__ int s_bp[NOBJ];
    const int b = blockIdx.y;
    const int a = blockIdx.x * 256 + threadIdx.x;
    if (threadIdx.x < NOBJ) {
        float4 t = truths[b * NOBJ + threadIdx.x];
        s_t[threadIdx.x] = t;
        s_area[threadIdx.x] = (t.z - t.x) * (t.w - t.y);
        s_lab[threadIdx.x] = labels[b * NOBJ + threadIdx.x];
        unsigned long long k = bp_key[b * NOBJ + threadIdx.x];
        unsigned int ia = 0xFFFFFFFFu - (unsigned int)(k & 0xFFFFFFFFull);
        s_bp[threadIdx.x] = (ia >= A_COUNT) ? -1 : (int)ia;
    }
    __syncthreads();
    float4 an = anchors[a];
    float ax0 = an.x - an.z * 0.5f, ay0 = an.y - an.w * 0.5f;
    float ax1 = an.x + an.z * 0.5f, ay1 = an.y + an.w * 0.5f;
    float area_p = (ax1 - ax0) * (ay1 - ay0);
    float best = -1.0f;
    int idx = 0;
#pragma unroll
    for (int n = 0; n < NOBJ; ++n) {
        float4 t = s_t[n];
        float lx = fmaxf(t.x, ax0), ly = fmaxf(t.y, ay0);
        float rx = fminf(t.z, ax1), ry = fminf(t.w, ay1);
        float w = fmaxf(rx - lx, 0.0f), h = fmaxf(ry - ly, 0.0f);
        float inter = w * h;
        float iou = inter / (s_area[n] + area_p - inter);
        if (iou > best) { best = iou; idx = n; }   // first-occurrence argmax over n
    }
#pragma unroll
    for (int n = 0; n < NOBJ; ++n) {
        if (s_bp[n] == a) { best = 2.0f; idx = n; }  // forced match, last n wins
    }
    const int conf = (best < 0.5f) ? 0 : s_lab[idx];

    float loc_l = 0.0f;
    int pos = 0;
    if (conf > 0) {
        pos = 1;
        float4 t = s_t[idx];
        float gx = ((t.x + t.z) * 0.5f - an.x) / (0.1f * an.z);
        float gy = ((t.y + t.w) * 0.5f - an.y) / (0.1f * an.w);
        float gw = __logf((t.z - t.x) / an.z) * 5.0f;
        float gh = __logf((t.w - t.y) / an.w) * 5.0f;
        float4 lp = locp[b * A_COUNT + a];
        loc_l = sl1(lp.x - gx) + sl1(lp.y - gy) + sl1(lp.z - gw) + sl1(lp.w - gh);
    }

    const float* cp = cls + (size_t)(b * A_COUNT + a) * C_COUNT;
    float cls_l = 0.0f;
#pragma unroll
    for (int c = 1; c < C_COUNT; ++c) {
        float x = cp[c];
        bool t = (conf == c);
        float e = __expf(-fabsf(x));
        float q = __builtin_amdgcn_rcpf(1.0f + e);  // sigmoid(|x|)
        float p = (x >= 0.0f) ? q : 1.0f - q;       // sigmoid(x)
        float pt = t ? p : (1.0f - p);
        float om = 1.0f - pt;
        float w = om * om * (t ? 0.25f : 0.75f);
        float bce = fmaxf(x, 0.0f) - (t ? x : 0.0f) + __logf(1.0f + e);
        cls_l += w * bce;
    }

    // wave reduction
#pragma unroll
    for (int s = 32; s >= 1; s >>= 1) {
        cls_l += __shfl_xor(cls_l, s);
        loc_l += __shfl_xor(loc_l, s);
        pos += __shfl_xor(pos, s);
    }
    if ((threadIdx.x & 63) == 0) {
        atomicAdd(&sums[0], (double)cls_l);
        atomicAdd(&sums[1], (double)loc_l);
        atomicAdd(cnt, (unsigned int)pos);
    }
}

__global__ void k_final(const double* __restrict__ sums, const unsigned int* __restrict__ cnt,
                        float* __restrict__ out) {
    float n = (float)*cnt;
    float c = (float)(sums[0]) / n;
    float l = (float)(sums[1]) / n;
    out[0] = c;
    out[1] = l;
    out[2] = c + l;
}

extern "C" void kernel_launch(void* const* d_in, const int* in_sizes, int n_in,
                              void* d_out, int out_size, void* d_ws, size_t ws_size,
                              hipStream_t stream) {
    const float* cls = (const float*)d_in[0];
    const float4* locp = (const float4*)d_in[1];
    const float4* truths = (const float4*)d_in[2];
    const float4* anchors = (const float4*)d_in[3];
    const int* labels = (const int*)d_in[4];

    unsigned long long* bp_key = (unsigned long long*)d_ws;
    double* sums = (double*)((char*)d_ws + 4096);
    unsigned int* cnt = (unsigned int*)((char*)d_ws + 4096 + 16);

    hipMemsetAsync(d_ws, 0, 8192, stream);

    dim3 grid(A_COUNT / 256, B_COUNT);
    k_match<<<grid, 256, 0, stream>>>(anchors, truths, bp_key);
    k_loss<<<grid, 256, 0, stream>>>(cls, locp, truths, anchors, labels, bp_key, sums, cnt);
    k_final<<<1, 1, 0, stream>>>(sums, cnt, (float*)d_out);
}

// Round 2
// 76.952 us; speedup vs baseline: 7.2085x; 7.2085x over previous
//
#include <hip/hip_runtime.h>

#define A_COUNT 24576
#define B_COUNT 32
#define NOBJ 16
#define C_COUNT 21

#define NB_CONF 3072   // 96 x 32 blocks in k_conf
#define NB_FOCAL 2048  // blocks in k_focal
#define TOTAL4 (B_COUNT * A_COUNT * C_COUNT / 4)  // 4128768 float4 elements

// ---- workspace layout (bytes) ----
// 0        : bp_key  u64 [B*NOBJ]           (4 KB)
// 4096     : conf    u8  [B*A]              (768 KB)
// 790528   : loc_partial f32 [NB_CONF]      (12 KB)
// 802816   : pos_partial u32 [NB_CONF]      (12 KB)
// 815104   : cls_partial f32 [NB_FOCAL]     (8 KB)
#define WS_BPKEY 0
#define WS_CONF 4096
#define WS_LOCP 790528
#define WS_POSP 802816
#define WS_CLSP 815104

__device__ __forceinline__ unsigned long long pack_key(float iou, int a) {
    unsigned int ib = __float_as_uint(iou);  // iou >= 0 so uint order == float order
    return ((unsigned long long)ib << 32) | (unsigned long long)(0xFFFFFFFFu - (unsigned int)a);
}

// Kernel 1: one block per (truth n, batch b): argmax over anchors of IoU,
// smallest-a tie-break. No atomics.
__global__ __launch_bounds__(256) void k_match(const float4* __restrict__ anchors,
                                               const float4* __restrict__ truths,
                                               unsigned long long* __restrict__ bp_key) {
    const int n = blockIdx.x;  // truth index
    const int b = blockIdx.y;
    float4 t = truths[b * NOBJ + n];
    const float area_t = (t.z - t.x) * (t.w - t.y);
    unsigned long long best = 0;
    for (int a = threadIdx.x; a < A_COUNT; a += 256) {
        float4 an = anchors[a];
        float ax0 = an.x - an.z * 0.5f, ay0 = an.y - an.w * 0.5f;
        float ax1 = an.x + an.z * 0.5f, ay1 = an.y + an.w * 0.5f;
        float area_p = (ax1 - ax0) * (ay1 - ay0);
        float lx = fmaxf(t.x, ax0), ly = fmaxf(t.y, ay0);
        float rx = fminf(t.z, ax1), ry = fminf(t.w, ay1);
        float w = fmaxf(rx - lx, 0.0f), h = fmaxf(ry - ly, 0.0f);
        float inter = w * h;
        float iou = inter / (area_t + area_p - inter);
        unsigned long long k = pack_key(iou, a);
        best = (k > best) ? k : best;
    }
#pragma unroll
    for (int s = 32; s >= 1; s >>= 1) {
        unsigned long long o = __shfl_xor(best, s);
        best = (o > best) ? o : best;
    }
    __shared__ unsigned long long s_best[4];
    if ((threadIdx.x & 63) == 0) s_best[threadIdx.x >> 6] = best;
    __syncthreads();
    if (threadIdx.x == 0) {
        best = s_best[0];
#pragma unroll
        for (int i = 1; i < 4; ++i) best = (s_best[i] > best) ? s_best[i] : best;
        bp_key[b * NOBJ + n] = best;
    }
}

__device__ __forceinline__ float sl1(float d) {
    float ad = fabsf(d);
    return (ad < 1.0f) ? 0.5f * d * d : ad - 0.5f;
}

// Kernel 2: per-anchor match + forced override + conf (u8) + smooth-L1 partials.
__global__ __launch_bounds__(256) void k_conf(const float4* __restrict__ locp,
                                              const float4* __restrict__ truths,
                                              const float4* __restrict__ anchors,
                                              const int* __restrict__ labels,
                                              const unsigned long long* __restrict__ bp_key,
                                              unsigned char* __restrict__ conf_out,
                                              float* __restrict__ loc_partial,
                                              unsigned int* __restrict__ pos_partial) {
    __shared__ float4 s_t[NOBJ];
    __shared__ float s_area[NOBJ];
    __shared__ int s_lab[NOBJ];
    __shared__ int s_bp[NOBJ];
    const int b = blockIdx.y;
    const int a = blockIdx.x * 256 + threadIdx.x;
    if (threadIdx.x < NOBJ) {
        float4 t = truths[b * NOBJ + threadIdx.x];
        s_t[threadIdx.x] = t;
        s_area[threadIdx.x] = (t.z - t.x) * (t.w - t.y);
        s_lab[threadIdx.x] = labels[b * NOBJ + threadIdx.x];
        unsigned long long k = bp_key[b * NOBJ + threadIdx.x];
        unsigned int ia = 0xFFFFFFFFu - (unsigned int)(k & 0xFFFFFFFFull);
        s_bp[threadIdx.x] = (ia >= A_COUNT) ? -1 : (int)ia;
    }
    __syncthreads();
    float4 an = anchors[a];
    float ax0 = an.x - an.z * 0.5f, ay0 = an.y - an.w * 0.5f;
    float ax1 = an.x + an.z * 0.5f, ay1 = an.y + an.w * 0.5f;
    float area_p = (ax1 - ax0) * (ay1 - ay0);
    float best = -1.0f;
    int idx = 0;
#pragma unroll
    for (int n = 0; n < NOBJ; ++n) {
        float4 t = s_t[n];
        float lx = fmaxf(t.x, ax0), ly = fmaxf(t.y, ay0);
        float rx = fminf(t.z, ax1), ry = fminf(t.w, ay1);
        float w = fmaxf(rx - lx, 0.0f), h = fmaxf(ry - ly, 0.0f);
        float inter = w * h;
        float iou = inter / (s_area[n] + area_p - inter);
        if (iou > best) { best = iou; idx = n; }   // first-occurrence argmax over n
    }
#pragma unroll
    for (int n = 0; n < NOBJ; ++n) {
        if (s_bp[n] == a) { best = 2.0f; idx = n; }  // forced match, last n wins
    }
    const int conf = (best < 0.5f) ? 0 : s_lab[idx];
    conf_out[b * A_COUNT + a] = (unsigned char)conf;

    float loc_l = 0.0f;
    unsigned int pos = 0;
    if (conf > 0) {
        pos = 1;
        float4 t = s_t[idx];
        float gx = ((t.x + t.z) * 0.5f - an.x) / (0.1f * an.z);
        float gy = ((t.y + t.w) * 0.5f - an.y) / (0.1f * an.w);
        float gw = __logf((t.z - t.x) / an.z) * 5.0f;
        float gh = __logf((t.w - t.y) / an.w) * 5.0f;
        float4 lp = locp[b * A_COUNT + a];
        loc_l = sl1(lp.x - gx) + sl1(lp.y - gy) + sl1(lp.z - gw) + sl1(lp.w - gh);
    }

    // block reduction -> one partial per block, no atomics
#pragma unroll
    for (int s = 32; s >= 1; s >>= 1) {
        loc_l += __shfl_xor(loc_l, s);
        pos += __shfl_xor(pos, s);
    }
    __shared__ float s_loc[4];
    __shared__ unsigned int s_pos[4];
    if ((threadIdx.x & 63) == 0) {
        s_loc[threadIdx.x >> 6] = loc_l;
        s_pos[threadIdx.x >> 6] = pos;
    }
    __syncthreads();
    if (threadIdx.x == 0) {
        float l = s_loc[0] + s_loc[1] + s_loc[2] + s_loc[3];
        unsigned int p = s_pos[0] + s_pos[1] + s_pos[2] + s_pos[3];
        int bid = blockIdx.y * gridDim.x + blockIdx.x;
        loc_partial[bid] = l;
        pos_partial[bid] = p;
    }
}

// Kernel 3: focal loss, fully coalesced float4 walk of the flat logit array.
__global__ __launch_bounds__(256) void k_focal(const float4* __restrict__ cls4,
                                               const unsigned char* __restrict__ conf,
                                               float* __restrict__ cls_partial) {
    float acc = 0.0f;
    const int stride = gridDim.x * 256;
    for (int i = blockIdx.x * 256 + threadIdx.x; i < TOTAL4; i += stride) {
        float4 x4 = cls4[i];
        unsigned int base = (unsigned int)i * 4u;
        unsigned int d = base / 21u;        // anchor index (magic-mul)
        unsigned int r = base - d * 21u;    // class column
        float xs[4] = {x4.x, x4.y, x4.z, x4.w};
#pragma unroll
        for (int j = 0; j < 4; ++j) {
            float x = xs[j];
            if (r != 0u) {                  // skip background column
                bool t = ((unsigned int)conf[d] == r);
                float e = __expf(-fabsf(x));
                float q = __builtin_amdgcn_rcpf(1.0f + e);  // sigmoid(|x|)
                float p = (x >= 0.0f) ? q : 1.0f - q;       // sigmoid(x)
                float pt = t ? p : (1.0f - p);
                float om = 1.0f - pt;
                float w = om * om * (t ? 0.25f : 0.75f);
                float bce = fmaxf(x, 0.0f) - (t ? x : 0.0f) + __logf(1.0f + e);
                acc += w * bce;
            }
            ++r;
            if (r == 21u) { r = 0u; ++d; }
        }
    }
#pragma unroll
    for (int s = 32; s >= 1; s >>= 1) acc += __shfl_xor(acc, s);
    __shared__ float s_acc[4];
    if ((threadIdx.x & 63) == 0) s_acc[threadIdx.x >> 6] = acc;
    __syncthreads();
    if (threadIdx.x == 0)
        cls_partial[blockIdx.x] = s_acc[0] + s_acc[1] + s_acc[2] + s_acc[3];
}

// Kernel 4: deterministic final reduction in double.
__global__ __launch_bounds__(256) void k_final(const float* __restrict__ loc_partial,
                                               const unsigned int* __restrict__ pos_partial,
                                               const float* __restrict__ cls_partial,
                                               float* __restrict__ out) {
    double loc = 0.0, clsv = 0.0;
    unsigned int pos = 0;
    for (int i = threadIdx.x; i < NB_CONF; i += 256) {
        loc += (double)loc_partial[i];
        pos += pos_partial[i];
    }
    for (int i = threadIdx.x; i < NB_FOCAL; i += 256) clsv += (double)cls_partial[i];
#pragma unroll
    for (int s = 32; s >= 1; s >>= 1) {
        loc += __shfl_xor(loc, s);
        clsv += __shfl_xor(clsv, s);
        pos += __shfl_xor(pos, s);
    }
    __shared__ double s_l[4], s_c[4];
    __shared__ unsigned int s_p[4];
    if ((threadIdx.x & 63) == 0) {
        s_l[threadIdx.x >> 6] = loc;
        s_c[threadIdx.x >> 6] = clsv;
        s_p[threadIdx.x >> 6] = pos;
    }
    __syncthreads();
    if (threadIdx.x == 0) {
        double l = s_l[0] + s_l[1] + s_l[2] + s_l[3];
        double c = s_c[0] + s_c[1] + s_c[2] + s_c[3];
        float n = (float)(s_p[0] + s_p[1] + s_p[2] + s_p[3]);
        float cf = (float)c / n;
        float lf = (float)l / n;
        out[0] = cf;
        out[1] = lf;
        out[2] = cf + lf;
    }
}

extern "C" void kernel_launch(void* const* d_in, const int* in_sizes, int n_in,
                              void* d_out, int out_size, void* d_ws, size_t ws_size,
                              hipStream_t stream) {
    const float4* cls4 = (const float4*)d_in[0];
    const float4* locp = (const float4*)d_in[1];
    const float4* truths = (const float4*)d_in[2];
    const float4* anchors = (const float4*)d_in[3];
    const int* labels = (const int*)d_in[4];

    char* ws = (char*)d_ws;
    unsigned long long* bp_key = (unsigned long long*)(ws + WS_BPKEY);
    unsigned char* conf = (unsigned char*)(ws + WS_CONF);
    float* loc_partial = (float*)(ws + WS_LOCP);
    unsigned int* pos_partial = (unsigned int*)(ws + WS_POSP);
    float* cls_partial = (float*)(ws + WS_CLSP);

    k_match<<<dim3(NOBJ, B_COUNT), 256, 0, stream>>>(anchors, truths, bp_key);
    k_conf<<<dim3(A_COUNT / 256, B_COUNT), 256, 0, stream>>>(locp, truths, anchors, labels,
                                                             bp_key, conf, loc_partial, pos_partial);
    k_focal<<<NB_FOCAL, 256, 0, stream>>>((const float4*)cls4, conf, cls_partial);
    k_final<<<1, 256, 0, stream>>>(loc_partial, pos_partial, cls_partial, (float*)d_out);
}

// Round 3
// 57.950 us; speedup vs baseline: 9.5722x; 1.3279x over previous
//
#include <hip/hip_runtime.h>

#define A_COUNT 24576
#define B_COUNT 32
#define NOBJ 16
#define C_COUNT 21

#define NCH 16          // anchor chunks in k_match
#define CHUNK (A_COUNT / NCH)   // 1536
#define NB_CONF 3072    // 96 x 32 blocks in k_conf
#define NB_FOCAL 2048   // blocks in k_focal
#define TOTAL4 (B_COUNT * A_COUNT * C_COUNT / 4)  // 4128768 float4 elements

// ---- workspace layout (bytes) ----
// 0        : bp_partial u64 [B*NOBJ][NCH]   (64 KB)
// 65536    : conf    u8  [B*A]              (768 KB)
// 851968   : loc_partial f32 [NB_CONF]      (12 KB)
// 864256   : pos_partial u32 [NB_CONF]      (12 KB)
// 876544   : cls_partial f32 [NB_FOCAL]     (8 KB)
#define WS_BPP 0
#define WS_CONF 65536
#define WS_LOCP 851968
#define WS_POSP 864256
#define WS_CLSP 876544

__device__ __forceinline__ unsigned long long pack_key(float iou, int a) {
    unsigned int ib = __float_as_uint(iou);  // iou >= 0 so uint order == float order
    return ((unsigned long long)ib << 32) | (unsigned long long)(0xFFFFFFFFu - (unsigned int)a);
}

// Kernel 1: per (truth n, batch b, anchor-chunk ch) block: partial argmax of IoU
// over the chunk's anchors (smallest-a tie-break). No atomics; every partial
// written unconditionally each call.
__global__ __launch_bounds__(256) void k_match(const float4* __restrict__ anchors,
                                               const float4* __restrict__ truths,
                                               unsigned long long* __restrict__ bp_partial) {
    const int n = blockIdx.x;  // truth index
    const int b = blockIdx.y;
    const int ch = blockIdx.z;
    float4 t = truths[b * NOBJ + n];
    const float area_t = (t.z - t.x) * (t.w - t.y);
    unsigned long long best = 0;
    const int a0 = ch * CHUNK;
#pragma unroll
    for (int k = 0; k < CHUNK / 256; ++k) {
        int a = a0 + k * 256 + threadIdx.x;
        float4 an = anchors[a];
        float ax0 = an.x - an.z * 0.5f, ay0 = an.y - an.w * 0.5f;
        float ax1 = an.x + an.z * 0.5f, ay1 = an.y + an.w * 0.5f;
        float area_p = (ax1 - ax0) * (ay1 - ay0);
        float lx = fmaxf(t.x, ax0), ly = fmaxf(t.y, ay0);
        float rx = fminf(t.z, ax1), ry = fminf(t.w, ay1);
        float w = fmaxf(rx - lx, 0.0f), h = fmaxf(ry - ly, 0.0f);
        float inter = w * h;
        float iou = inter / (area_t + area_p - inter);
        unsigned long long key = pack_key(iou, a);
        best = (key > best) ? key : best;
    }
#pragma unroll
    for (int s = 32; s >= 1; s >>= 1) {
        unsigned long long o = __shfl_xor(best, s);
        best = (o > best) ? o : best;
    }
    __shared__ unsigned long long s_best[4];
    if ((threadIdx.x & 63) == 0) s_best[threadIdx.x >> 6] = best;
    __syncthreads();
    if (threadIdx.x == 0) {
        best = s_best[0];
#pragma unroll
        for (int i = 1; i < 4; ++i) best = (s_best[i] > best) ? s_best[i] : best;
        bp_partial[(b * NOBJ + n) * NCH + ch] = best;
    }
}

__device__ __forceinline__ float sl1(float d) {
    float ad = fabsf(d);
    return (ad < 1.0f) ? 0.5f * d * d : ad - 0.5f;
}

// Kernel 2: per-anchor match + forced override + conf (u8) + smooth-L1 partials.
__global__ __launch_bounds__(256) void k_conf(const float4* __restrict__ locp,
                                              const float4* __restrict__ truths,
                                              const float4* __restrict__ anchors,
                                              const int* __restrict__ labels,
                                              const unsigned long long* __restrict__ bp_partial,
                                              unsigned char* __restrict__ conf_out,
                                              float* __restrict__ loc_partial,
                                              unsigned int* __restrict__ pos_partial) {
    __shared__ float4 s_t[NOBJ];
    __shared__ float s_area[NOBJ];
    __shared__ int s_lab[NOBJ];
    __shared__ int s_bp[NOBJ];
    const int b = blockIdx.y;
    const int a = blockIdx.x * 256 + threadIdx.x;
    if (threadIdx.x < NOBJ) {
        float4 t = truths[b * NOBJ + threadIdx.x];
        s_t[threadIdx.x] = t;
        s_area[threadIdx.x] = (t.z - t.x) * (t.w - t.y);
        s_lab[threadIdx.x] = labels[b * NOBJ + threadIdx.x];
        unsigned long long best = 0;
#pragma unroll
        for (int ch = 0; ch < NCH; ++ch) {
            unsigned long long v = bp_partial[(b * NOBJ + threadIdx.x) * NCH + ch];
            best = (v > best) ? v : best;
        }
        unsigned int ia = 0xFFFFFFFFu - (unsigned int)(best & 0xFFFFFFFFull);
        s_bp[threadIdx.x] = (ia >= A_COUNT) ? -1 : (int)ia;
    }
    __syncthreads();
    float4 an = anchors[a];
    float ax0 = an.x - an.z * 0.5f, ay0 = an.y - an.w * 0.5f;
    float ax1 = an.x + an.z * 0.5f, ay1 = an.y + an.w * 0.5f;
    float area_p = (ax1 - ax0) * (ay1 - ay0);
    float best = -1.0f;
    int idx = 0;
#pragma unroll
    for (int n = 0; n < NOBJ; ++n) {
        float4 t = s_t[n];
        float lx = fmaxf(t.x, ax0), ly = fmaxf(t.y, ay0);
        float rx = fminf(t.z, ax1), ry = fminf(t.w, ay1);
        float w = fmaxf(rx - lx, 0.0f), h = fmaxf(ry - ly, 0.0f);
        float inter = w * h;
        float iou = inter / (s_area[n] + area_p - inter);
        if (iou > best) { best = iou; idx = n; }   // first-occurrence argmax over n
    }
#pragma unroll
    for (int n = 0; n < NOBJ; ++n) {
        if (s_bp[n] == a) { best = 2.0f; idx = n; }  // forced match, last n wins
    }
    const int conf = (best < 0.5f) ? 0 : s_lab[idx];
    conf_out[b * A_COUNT + a] = (unsigned char)conf;

    float loc_l = 0.0f;
    unsigned int pos = 0;
    if (conf > 0) {
        pos = 1;
        float4 t = s_t[idx];
        float gx = ((t.x + t.z) * 0.5f - an.x) / (0.1f * an.z);
        float gy = ((t.y + t.w) * 0.5f - an.y) / (0.1f * an.w);
        float gw = __logf((t.z - t.x) / an.z) * 5.0f;
        float gh = __logf((t.w - t.y) / an.w) * 5.0f;
        float4 lp = locp[b * A_COUNT + a];
        loc_l = sl1(lp.x - gx) + sl1(lp.y - gy) + sl1(lp.z - gw) + sl1(lp.w - gh);
    }

    // block reduction -> one partial per block, no atomics
#pragma unroll
    for (int s = 32; s >= 1; s >>= 1) {
        loc_l += __shfl_xor(loc_l, s);
        pos += __shfl_xor(pos, s);
    }
    __shared__ float s_loc[4];
    __shared__ unsigned int s_pos[4];
    if ((threadIdx.x & 63) == 0) {
        s_loc[threadIdx.x >> 6] = loc_l;
        s_pos[threadIdx.x >> 6] = pos;
    }
    __syncthreads();
    if (threadIdx.x == 0) {
        float l = s_loc[0] + s_loc[1] + s_loc[2] + s_loc[3];
        unsigned int p = s_pos[0] + s_pos[1] + s_pos[2] + s_pos[3];
        int bid = blockIdx.y * gridDim.x + blockIdx.x;
        loc_partial[bid] = l;
        pos_partial[bid] = p;
    }
}

// Kernel 3: focal loss, fully coalesced float4 walk of the flat logit array.
__global__ __launch_bounds__(256) void k_focal(const float4* __restrict__ cls4,
                                               const unsigned char* __restrict__ conf,
                                               float* __restrict__ cls_partial) {
    float acc = 0.0f;
    const int stride = gridDim.x * 256;
    for (int i = blockIdx.x * 256 + threadIdx.x; i < TOTAL4; i += stride) {
        float4 x4 = cls4[i];
        unsigned int base = (unsigned int)i * 4u;
        unsigned int d = base / 21u;        // anchor index (magic-mul)
        unsigned int r = base - d * 21u;    // class column
        float xs[4] = {x4.x, x4.y, x4.z, x4.w};
#pragma unroll
        for (int j = 0; j < 4; ++j) {
            float x = xs[j];
            if (r != 0u) {                  // skip background column
                bool t = ((unsigned int)conf[d] == r);
                float e = __expf(-fabsf(x));
                float q = __builtin_amdgcn_rcpf(1.0f + e);  // sigmoid(|x|)
                float p = (x >= 0.0f) ? q : 1.0f - q;       // sigmoid(x)
                float pt = t ? p : (1.0f - p);
                float om = 1.0f - pt;
                float w = om * om * (t ? 0.25f : 0.75f);
                float bce = fmaxf(x, 0.0f) - (t ? x : 0.0f) + __logf(1.0f + e);
                acc += w * bce;
            }
            ++r;
            if (r == 21u) { r = 0u; ++d; }
        }
    }
#pragma unroll
    for (int s = 32; s >= 1; s >>= 1) acc += __shfl_xor(acc, s);
    __shared__ float s_acc[4];
    if ((threadIdx.x & 63) == 0) s_acc[threadIdx.x >> 6] = acc;
    __syncthreads();
    if (threadIdx.x == 0)
        cls_partial[blockIdx.x] = s_acc[0] + s_acc[1] + s_acc[2] + s_acc[3];
}

// Kernel 4: deterministic final reduction in double.
__global__ __launch_bounds__(256) void k_final(const float* __restrict__ loc_partial,
                                               const unsigned int* __restrict__ pos_partial,
                                               const float* __restrict__ cls_partial,
                                               float* __restrict__ out) {
    double loc = 0.0, clsv = 0.0;
    unsigned int pos = 0;
    for (int i = threadIdx.x; i < NB_CONF; i += 256) {
        loc += (double)loc_partial[i];
        pos += pos_partial[i];
    }
    for (int i = threadIdx.x; i < NB_FOCAL; i += 256) clsv += (double)cls_partial[i];
#pragma unroll
    for (int s = 32; s >= 1; s >>= 1) {
        loc += __shfl_xor(loc, s);
        clsv += __shfl_xor(clsv, s);
        pos += __shfl_xor(pos, s);
    }
    __shared__ double s_l[4], s_c[4];
    __shared__ unsigned int s_p[4];
    if ((threadIdx.x & 63) == 0) {
        s_l[threadIdx.x >> 6] = loc;
        s_c[threadIdx.x >> 6] = clsv;
        s_p[threadIdx.x >> 6] = pos;
    }
    __syncthreads();
    if (threadIdx.x == 0) {
        double l = s_l[0] + s_l[1] + s_l[2] + s_l[3];
        double c = s_c[0] + s_c[1] + s_c[2] + s_c[3];
        float n = (float)(s_p[0] + s_p[1] + s_p[2] + s_p[3]);
        float cf = (float)c / n;
        float lf = (float)l / n;
        out[0] = cf;
        out[1] = lf;
        out[2] = cf + lf;
    }
}

extern "C" void kernel_launch(void* const* d_in, const int* in_sizes, int n_in,
                              void* d_out, int out_size, void* d_ws, size_t ws_size,
                              hipStream_t stream) {
    const float4* cls4 = (const float4*)d_in[0];
    const float4* locp = (const float4*)d_in[1];
    const float4* truths = (const float4*)d_in[2];
    const float4* anchors = (const float4*)d_in[3];
    const int* labels = (const int*)d_in[4];

    char* ws = (char*)d_ws;
    unsigned long long* bp_partial = (unsigned long long*)(ws + WS_BPP);
    unsigned char* conf = (unsigned char*)(ws + WS_CONF);
    float* loc_partial = (float*)(ws + WS_LOCP);
    unsigned int* pos_partial = (unsigned int*)(ws + WS_POSP);
    float* cls_partial = (float*)(ws + WS_CLSP);

    k_match<<<dim3(NOBJ, B_COUNT, NCH), 256, 0, stream>>>(anchors, truths, bp_partial);
    k_conf<<<dim3(A_COUNT / 256, B_COUNT), 256, 0, stream>>>(locp, truths, anchors, labels,
                                                             bp_partial, conf, loc_partial, pos_partial);
    k_focal<<<NB_FOCAL, 256, 0, stream>>>(cls4, conf, cls_partial);
    k_final<<<1, 256, 0, stream>>>(loc_partial, pos_partial, cls_partial, (float*)d_out);
}